// Round 19
// baseline (531.136 us; speedup 1.0000x reference)
//
#include <hip/hip_runtime.h>
#include <hip/hip_bf16.h>
#include <stdint.h>

#define NATOMS 50000
#define NINT   800000
#define NFM    128
#define VOFF   (NATOMS*NFM)
#define NBLK   (NINT/256)    // 3125 (filter)
#define CBLK   (NINT/128)    // 6250 (conv)

typedef __bf16 bf16x8 __attribute__((ext_vector_type(8)));
typedef float  f32x4  __attribute__((ext_vector_type(4)));
typedef unsigned short u16;
typedef u16 u16x8 __attribute__((ext_vector_type(8)));
typedef u16 u16x4 __attribute__((ext_vector_type(4)));

__device__ __forceinline__ u16 f2b(float f){
  __bf16 h = (__bf16)f;
  return __builtin_bit_cast(u16, h);
}
__device__ __forceinline__ float b2f(u16 v){
  return (float)__builtin_bit_cast(__bf16, v);
}

__device__ __forceinline__ float sspf(float x){
  // ssp(x) = ln((1+e^x)/2) = ln2*(log2(1+2^(x*log2e)) - 1); safe for |x|<88
  float t = exp2f(x * 1.44269504088896f);
  return 0.69314718055995f * (log2f(1.0f + t) - 1.0f);
}

// ---- fast zero for conv ----
__global__ void zero_k(float4* __restrict__ p, int n4){
  int i = blockIdx.x * blockDim.x + threadIdx.x;
  int stride = gridDim.x * blockDim.x;
  float4 z = make_float4(0.f, 0.f, 0.f, 0.f);
  for (; i < n4; i += stride) p[i] = z;
}

// ---- weight prep: transpose 128x128 f32 -> bf16 Wt[n][k] = W[k][n] ----
__global__ void prep_weights_k(const float* __restrict__ w0, const float* __restrict__ w1,
                               const float* __restrict__ w2, const float* __restrict__ w3,
                               const float* __restrict__ w4, u16* __restrict__ wt){
  const float* srcs[5] = {w0, w1, w2, w3, w4};
  const float* src = srcs[blockIdx.x];
  u16* dst = wt + (size_t)blockIdx.x * NFM * NFM;
  for (int i = threadIdx.x; i < NFM*NFM; i += blockDim.x){
    int n = i >> 7, k = i & 127;
    dst[i] = f2b(src[k*NFM + n]);
  }
}

// ---- stage 256x128 f32 rows -> swizzled bf16 LDS tile (512 threads) ----
__device__ __forceinline__ void stage_inp(u16* lsA, const float* __restrict__ src,
                                          int base_row, int n_total, int t){
  #pragma unroll
  for (int pp = 0; pp < 8; ++pp){
    int id  = pp*512 + t;
    int row = id >> 4, c = id & 15;
    int grow = base_row + row;
    float4 v0 = make_float4(0.f,0.f,0.f,0.f), v1 = v0;
    if (grow < n_total){
      const float4* gp = reinterpret_cast<const float4*>(src + (size_t)grow*NFM + c*8);
      v0 = gp[0]; v1 = gp[1];
    }
    u16x8 pk;
    pk[0]=f2b(v0.x); pk[1]=f2b(v0.y); pk[2]=f2b(v0.z); pk[3]=f2b(v0.w);
    pk[4]=f2b(v1.x); pk[5]=f2b(v1.y); pk[6]=f2b(v1.z); pk[7]=f2b(v1.w);
    int byte = row*256 + ((c*16) ^ ((row & 7) << 4));
    *reinterpret_cast<u16x8*>(reinterpret_cast<char*>(lsA) + byte) = pk;
  }
}

// ---- stage 128x128 bf16 weight tile -> swizzled LDS (512 threads) ----
__device__ __forceinline__ void stage_w(u16* lsW, const u16* __restrict__ wt, int t){
  #pragma unroll
  for (int pp = 0; pp < 4; ++pp){
    int id = pp*512 + t;
    int n = id >> 4, c = id & 15;
    u16x8 v = *reinterpret_cast<const u16x8*>(wt + n*NFM + c*8);
    int byte = n*256 + ((c*16) ^ ((n & 7) << 4));
    *reinterpret_cast<u16x8*>(reinterpret_cast<char*>(lsW) + byte) = v;
  }
}

// ---- per-wave 32x128 GEMM, A from swizzled LDS, B from LDS ----
__device__ __forceinline__ void gemm_tile(const u16* lsA, const u16* lsW,
                                          int wrow, int l15, int lk, f32x4 acc[2][8]){
  #pragma unroll
  for (int ks = 0; ks < 4; ++ks){
    int kb2 = (ks*32 + lk*8) * 2;
    int r0 = wrow + l15, r1 = wrow + 16 + l15;
    bf16x8 a0 = *reinterpret_cast<const bf16x8*>(reinterpret_cast<const char*>(lsA) + r0*256 + (kb2 ^ ((r0 & 7) << 4)));
    bf16x8 a1 = *reinterpret_cast<const bf16x8*>(reinterpret_cast<const char*>(lsA) + r1*256 + (kb2 ^ ((r1 & 7) << 4)));
    #pragma unroll
    for (int ni = 0; ni < 8; ++ni){
      int n = ni*16 + l15;
      bf16x8 b = *reinterpret_cast<const bf16x8*>(reinterpret_cast<const char*>(lsW) + n*256 + (kb2 ^ ((n & 7) << 4)));
      acc[0][ni] = __builtin_amdgcn_mfma_f32_16x16x32_bf16(a0, b, acc[0][ni], 0, 0, 0);
      acc[1][ni] = __builtin_amdgcn_mfma_f32_16x16x32_bf16(a1, b, acc[1][ni], 0, 0, 0);
    }
  }
}

// ---- f = x @ W_in2fac, output bf16 ----
__global__ __launch_bounds__(512, 2) void in2fac_k(const float* __restrict__ x,
                                                   const u16* __restrict__ wt,
                                                   u16* __restrict__ f_g){
  __shared__ u16 lsA[256*128];
  __shared__ u16 lsW[128*128];
  int t = threadIdx.x;
  int B0 = blockIdx.x * 256;
  stage_inp(lsA, x, B0, NATOMS, t);
  stage_w(lsW, wt, t);
  __syncthreads();
  int wid = t >> 6, lane = t & 63, l15 = lane & 15, lk = lane >> 4;
  int wrow = wid * 32;
  f32x4 acc[2][8] = {};
  gemm_tile(lsA, lsW, wrow, l15, lk, acc);
  #pragma unroll
  for (int mi = 0; mi < 2; ++mi)
    #pragma unroll
    for (int ni = 0; ni < 8; ++ni)
      #pragma unroll
      for (int j = 0; j < 4; ++j){
        int grow = B0 + wrow + mi*16 + lk*4 + j;
        if (grow < NATOMS) f_g[(size_t)grow*NFM + ni*16 + l15] = f2b(acc[mi][ni][j]);
      }
}

// ---- filter kernel: all 16 A-loads hoisted (nontemporal), 1 barrier ----
__global__ __launch_bounds__(512) __attribute__((amdgpu_waves_per_eu(4, 4)))
void filter_k(const float* __restrict__ dijk,
              const float* __restrict__ b_f1, const float* __restrict__ b_f2,
              const u16* __restrict__ wt1, const u16* __restrict__ wt2,
              u16* __restrict__ w_g){
  __shared__ u16 lsW[2*128*128];   // 64 KB: W1 | W2
  __shared__ u16 lsS[8192];        // 16 KB: 2 KB per-wave scratch
  int t = threadIdx.x;
  int B0 = blockIdx.x * 256;
  int wid = t >> 6, lane = t & 63, l15 = lane & 15, lk = lane >> 4;

  // issue ALL A loads first (16 f32x4/lane, nontemporal) -> overlap W staging
  f32x4 araw[16];
  {
    const float* abase = dijk + (size_t)(B0 + wid*32 + l15) * NFM;
    #pragma unroll
    for (int mi = 0; mi < 2; ++mi)
      #pragma unroll
      for (int ks = 0; ks < 4; ++ks){
        const f32x4* gp = reinterpret_cast<const f32x4*>(abase + mi*16*NFM + ks*32 + lk*8);
        araw[(mi*4+ks)*2+0] = __builtin_nontemporal_load(gp);
        araw[(mi*4+ks)*2+1] = __builtin_nontemporal_load(gp+1);
      }
  }

  stage_w(lsW, wt1, t);
  stage_w(lsW + 16384, wt2, t);

  float bias1[8], bias2[8];
  #pragma unroll
  for (int ni = 0; ni < 8; ++ni){ bias1[ni] = b_f1[ni*16 + l15]; bias2[ni] = b_f2[ni*16 + l15]; }

  // pack to bf16 fragments (araw dies here)
  bf16x8 aa[2][4];
  #pragma unroll
  for (int mi = 0; mi < 2; ++mi)
    #pragma unroll
    for (int ks = 0; ks < 4; ++ks){
      f32x4 v0 = araw[(mi*4+ks)*2], v1 = araw[(mi*4+ks)*2+1];
      u16x8 pk;
      pk[0]=f2b(v0[0]); pk[1]=f2b(v0[1]); pk[2]=f2b(v0[2]); pk[3]=f2b(v0[3]);
      pk[4]=f2b(v1[0]); pk[5]=f2b(v1[1]); pk[6]=f2b(v1[2]); pk[7]=f2b(v1[3]);
      aa[mi][ks] = __builtin_bit_cast(bf16x8, pk);
    }

  __syncthreads();   // W1+W2 ready; everything below is wave-private

  char* wbase = reinterpret_cast<char*>(lsS) + wid*2048;  // [16r][64c] bf16 swizzled
  const char* lsW1b = reinterpret_cast<const char*>(lsW);
  const char* lsW2b = reinterpret_cast<const char*>(lsW + 16384);

  #pragma unroll
  for (int mi = 0; mi < 2; ++mi){
    // GEMM1 full width
    f32x4 acc[8] = {};
    #pragma unroll
    for (int ks = 0; ks < 4; ++ks){
      int kb2 = (ks*32 + lk*8) * 2;
      #pragma unroll
      for (int ni = 0; ni < 8; ++ni){
        int n = ni*16 + l15;
        bf16x8 b = *reinterpret_cast<const bf16x8*>(lsW1b + n*256 + (kb2 ^ ((n & 7) << 4)));
        acc[ni] = __builtin_amdgcn_mfma_f32_16x16x32_bf16(aa[mi][ks], b, acc[ni], 0, 0, 0);
      }
    }
    // h = ssp(acc+b1) via scratch (2 col-halves), reload as k-fragments
    bf16x8 h[4];
    #pragma unroll
    for (int p = 0; p < 2; ++p){
      #pragma unroll
      for (int nn = 0; nn < 4; ++nn){
        int col = nn*16 + l15;
        #pragma unroll
        for (int j = 0; j < 4; ++j){
          int r = lk*4 + j;
          *reinterpret_cast<u16*>(wbase + r*128 + ((col*2) ^ ((r & 7) << 4))) = f2b(sspf(acc[p*4+nn][j] + bias1[p*4+nn]));
        }
      }
      #pragma unroll
      for (int ksl = 0; ksl < 2; ++ksl)
        h[p*2+ksl] = *reinterpret_cast<const bf16x8*>(wbase + l15*128 + ((ksl*64 + lk*16) ^ ((l15 & 7) << 4)));
    }
    // GEMM2 per 64-col half; ssp -> scratch -> coalesced 32B/lane global writes
    #pragma unroll
    for (int p = 0; p < 2; ++p){
      f32x4 acc2[4] = {};
      #pragma unroll
      for (int ks = 0; ks < 4; ++ks){
        int kb2 = (ks*32 + lk*8) * 2;
        #pragma unroll
        for (int nn = 0; nn < 4; ++nn){
          int n = (p*4 + nn)*16 + l15;
          bf16x8 b = *reinterpret_cast<const bf16x8*>(lsW2b + n*256 + (kb2 ^ ((n & 7) << 4)));
          acc2[nn] = __builtin_amdgcn_mfma_f32_16x16x32_bf16(h[ks], b, acc2[nn], 0, 0, 0);
        }
      }
      #pragma unroll
      for (int nn = 0; nn < 4; ++nn){
        int col = nn*16 + l15;
        #pragma unroll
        for (int j = 0; j < 4; ++j){
          int r = lk*4 + j;
          *reinterpret_cast<u16*>(wbase + r*128 + ((col*2) ^ ((r & 7) << 4))) = f2b(sspf(acc2[nn][j] + bias2[p*4+nn]));
        }
      }
      // full 64-col coverage — each lane writes 32 B (2 x u16x8)
      int row16 = lane & 15, chunk = lane >> 4;   // chunk 0..3 -> col base chunk*16
      u16x8 v0 = *reinterpret_cast<const u16x8*>(wbase + row16*128 + ((chunk*32) ^ ((row16 & 7) << 4)));
      u16x8 v1 = *reinterpret_cast<const u16x8*>(wbase + row16*128 + ((chunk*32 + 16) ^ ((row16 & 7) << 4)));
      u16* gdst = w_g + (size_t)(B0 + wid*32 + mi*16 + row16)*NFM + p*64 + chunk*16;
      *reinterpret_cast<u16x8*>(gdst)     = v0;
      *reinterpret_cast<u16x8*>(gdst + 8) = v1;
    }
  }
}

// ---- conv kernel v3: 8-row chains, 4 cols/thread (uint2), cached w reads ----
__global__ __launch_bounds__(512) void conv_k(const int* __restrict__ idx_j,
    const int* __restrict__ seg_i, const u16* __restrict__ f_g,
    const u16* __restrict__ w_g, float* __restrict__ conv){
  __shared__ int lsSeg[128];
  __shared__ int lsIdx[128];
  int t = threadIdx.x;
  int B0 = blockIdx.x * 128;
  if (t < 128){ lsSeg[t] = seg_i[B0 + t]; lsIdx[t] = idx_j[B0 + t]; }
  __syncthreads();
  int c4 = t & 31, q = t >> 5;          // col quad 0..31, chunk 0..15 (8 rows)
  int qs = q*8, qe = qs + 8;
  int gc = c4*4;
  int prevseg = (qs > 0) ? lsSeg[qs-1] : (B0 > 0 ? seg_i[B0-1] : -1);
  int nextseg = (qe < 128) ? lsSeg[qe] : (B0 + 128 < NINT ? seg_i[B0+128] : -1);
  const u16* wtile = w_g + (size_t)B0*NFM;
  float s0=0.f, s1=0.f, s2=0.f, s3=0.f;
  int cur = lsSeg[qs], rs = qs;
  #pragma unroll
  for (int r = qs; r < qe; ++r){
    int sg = lsSeg[r];
    uint2 wv = *reinterpret_cast<const uint2*>(wtile + (size_t)r*NFM + gc);
    uint2 fv = *reinterpret_cast<const uint2*>(f_g + (size_t)lsIdx[r]*NFM + gc);
    if (sg != cur){
      float* dp = conv + (size_t)cur*NFM + gc;
      if (rs == qs && prevseg == cur){
        atomicAdd(dp, s0); atomicAdd(dp+1, s1); atomicAdd(dp+2, s2); atomicAdd(dp+3, s3);
      } else {
        *reinterpret_cast<float4*>(dp) = make_float4(s0, s1, s2, s3);
      }
      cur = sg; rs = r; s0 = s1 = s2 = s3 = 0.f;
    }
    s0 = fmaf(b2f((u16)(wv.x & 0xffff)), b2f((u16)(fv.x & 0xffff)), s0);
    s1 = fmaf(b2f((u16)(wv.x >> 16)),   b2f((u16)(fv.x >> 16)),   s1);
    s2 = fmaf(b2f((u16)(wv.y & 0xffff)), b2f((u16)(fv.y & 0xffff)), s2);
    s3 = fmaf(b2f((u16)(wv.y >> 16)),   b2f((u16)(fv.y >> 16)),   s3);
  }
  float* dp = conv + (size_t)cur*NFM + gc;
  if ((rs == qs && prevseg == cur) || nextseg == cur){
    atomicAdd(dp, s0); atomicAdd(dp+1, s1); atomicAdd(dp+2, s2); atomicAdd(dp+3, s3);
  } else {
    *reinterpret_cast<float4*>(dp) = make_float4(s0, s1, s2, s3);
  }
}

// ---- c = ssp(conv@W3+b3); v = c@W4+b4; y = x+v; out = [y ; v] ----
__global__ __launch_bounds__(512, 2) void out_k(const float* __restrict__ conv,
    const float* __restrict__ x, const u16* __restrict__ wt3, const u16* __restrict__ wt4,
    const float* __restrict__ b3, const float* __restrict__ b4, float* __restrict__ out){
  __shared__ u16 lsA[256*128];
  __shared__ u16 lsW1[128*128];
  __shared__ u16 lsW2[128*128];
  int t = threadIdx.x;
  int B0 = blockIdx.x * 256;
  stage_inp(lsA, conv, B0, NATOMS, t);
  stage_w(lsW1, wt3, t);
  stage_w(lsW2, wt4, t);
  __syncthreads();
  int wid = t >> 6, lane = t & 63, l15 = lane & 15, lk = lane >> 4;
  int wrow = wid * 32;
  float bias3[8], bias4[8];
  #pragma unroll
  for (int ni = 0; ni < 8; ++ni){ bias3[ni] = b3[ni*16 + l15]; bias4[ni] = b4[ni*16 + l15]; }

  f32x4 acc1[2][8] = {};
  gemm_tile(lsA, lsW1, wrow, l15, lk, acc1);
  #pragma unroll
  for (int mi = 0; mi < 2; ++mi)
    #pragma unroll
    for (int ni = 0; ni < 8; ++ni)
      #pragma unroll
      for (int j = 0; j < 4; ++j){
        int row = wrow + mi*16 + lk*4 + j;
        int col = ni*16 + l15;
        u16 hb = f2b(sspf(acc1[mi][ni][j] + bias3[ni]));
        int byte = row*256 + ((col*2) ^ ((row & 7) << 4));
        *reinterpret_cast<u16*>(reinterpret_cast<char*>(lsA) + byte) = hb;
      }

  f32x4 acc2[2][8] = {};
  gemm_tile(lsA, lsW2, wrow, l15, lk, acc2);
  #pragma unroll
  for (int mi = 0; mi < 2; ++mi)
    #pragma unroll
    for (int ni = 0; ni < 8; ++ni)
      #pragma unroll
      for (int j = 0; j < 4; ++j){
        int grow = B0 + wrow + mi*16 + lk*4 + j;
        if (grow < NATOMS){
          int col = ni*16 + l15;
          float v = acc2[mi][ni][j] + bias4[ni];
          float yv = x[(size_t)grow*NFM + col] + v;
          out[(size_t)grow*NFM + col] = yv;
          out[(size_t)VOFF + (size_t)grow*NFM + col] = v;
        }
      }
}

extern "C" void kernel_launch(void* const* d_in, const int* in_sizes, int n_in,
                              void* d_out, int out_size, void* d_ws, size_t ws_size,
                              hipStream_t stream){
  const float* x        = (const float*)d_in[0];
  const float* dijk     = (const float*)d_in[1];
  const int*   idx_j    = (const int*)d_in[2];
  const int*   seg_i    = (const int*)d_in[3];
  // d_in[4] = seg_j (identity, unused), d_in[5] = seg_i_sum (unused)
  const float* W_f1     = (const float*)d_in[6];
  const float* b_f1     = (const float*)d_in[7];
  const float* W_f2     = (const float*)d_in[8];
  const float* b_f2     = (const float*)d_in[9];
  const float* W_in2fac = (const float*)d_in[10];
  const float* W_fac2o  = (const float*)d_in[11];
  const float* b_fac2o  = (const float*)d_in[12];
  const float* W_dense  = (const float*)d_in[13];
  const float* b_dense  = (const float*)d_in[14];
  float* out = (float*)d_out;

  char* ws = (char*)d_ws;
  u16*   f_g  = (u16*)ws;                         // 12.8 MB (bf16)
  float* conv = (float*)(ws + 12800000);          // 25.6 MB
  u16*   wt   = (u16*)(ws + 38400000);            // 5 x 32 KB
  u16*   w_g  = (u16*)(ws + 38600000);            // 204.8 MB (bf16, ~L3-resident)
  u16* wt1 = wt;             // W_f1^T
  u16* wt2 = wt + 16384;     // W_f2^T
  u16* wt5 = wt + 2*16384;   // W_in2fac^T
  u16* wt3 = wt + 3*16384;   // W_fac2out^T
  u16* wt4 = wt + 4*16384;   // W_dense^T

  prep_weights_k<<<5, 256, 0, stream>>>(W_f1, W_f2, W_in2fac, W_fac2o, W_dense, wt);
  zero_k<<<2048, 256, 0, stream>>>(reinterpret_cast<float4*>(conv), NATOMS*NFM/4);
  in2fac_k<<<(NATOMS + 255)/256, 512, 0, stream>>>(x, wt5, f_g);
  filter_k<<<NBLK, 512, 0, stream>>>(dijk, b_f1, b_f2, wt1, wt2, w_g);
  conv_k<<<CBLK, 512, 0, stream>>>(idx_j, seg_i, f_g, w_g, conv);
  out_k<<<(NATOMS + 255)/256, 512, 0, stream>>>(conv, x, wt3, wt4, b_fac2o, b_dense, out);
}

// Round 20
// 326.486 us; speedup vs baseline: 1.6268x; 1.6268x over previous
//
#include <hip/hip_runtime.h>
#include <hip/hip_bf16.h>
#include <stdint.h>

#define NATOMS 50000
#define NINT   800000
#define NFM    128
#define VOFF   (NATOMS*NFM)
#define NBLK   (NINT/256)          // 3125 (filter)
#define CVROWS 512
#define CVBLK  ((NINT + CVROWS - 1)/CVROWS)   // 1563 (conv)

typedef __bf16 bf16x8 __attribute__((ext_vector_type(8)));
typedef float  f32x4  __attribute__((ext_vector_type(4)));
typedef unsigned short u16;
typedef u16 u16x8 __attribute__((ext_vector_type(8)));
typedef u16 u16x4 __attribute__((ext_vector_type(4)));

__device__ __forceinline__ u16 f2b(float f){
  __bf16 h = (__bf16)f;
  return __builtin_bit_cast(u16, h);
}
__device__ __forceinline__ float b2f(u16 v){
  return (float)__builtin_bit_cast(__bf16, v);
}

__device__ __forceinline__ float sspf(float x){
  // ssp(x) = ln((1+e^x)/2) = ln2*(log2(1+2^(x*log2e)) - 1); safe for |x|<88
  float t = exp2f(x * 1.44269504088896f);
  return 0.69314718055995f * (log2f(1.0f + t) - 1.0f);
}

// ---- fast zero for conv ----
__global__ void zero_k(float4* __restrict__ p, int n4){
  int i = blockIdx.x * blockDim.x + threadIdx.x;
  int stride = gridDim.x * blockDim.x;
  float4 z = make_float4(0.f, 0.f, 0.f, 0.f);
  for (; i < n4; i += stride) p[i] = z;
}

// ---- weight prep: transpose 128x128 f32 -> bf16 Wt[n][k] = W[k][n] ----
__global__ void prep_weights_k(const float* __restrict__ w0, const float* __restrict__ w1,
                               const float* __restrict__ w2, const float* __restrict__ w3,
                               const float* __restrict__ w4, u16* __restrict__ wt){
  const float* srcs[5] = {w0, w1, w2, w3, w4};
  const float* src = srcs[blockIdx.x];
  u16* dst = wt + (size_t)blockIdx.x * NFM * NFM;
  for (int i = threadIdx.x; i < NFM*NFM; i += blockDim.x){
    int n = i >> 7, k = i & 127;
    dst[i] = f2b(src[k*NFM + n]);
  }
}

// ---- stage 256x128 f32 rows -> swizzled bf16 LDS tile (512 threads) ----
__device__ __forceinline__ void stage_inp(u16* lsA, const float* __restrict__ src,
                                          int base_row, int n_total, int t){
  #pragma unroll
  for (int pp = 0; pp < 8; ++pp){
    int id  = pp*512 + t;
    int row = id >> 4, c = id & 15;
    int grow = base_row + row;
    float4 v0 = make_float4(0.f,0.f,0.f,0.f), v1 = v0;
    if (grow < n_total){
      const float4* gp = reinterpret_cast<const float4*>(src + (size_t)grow*NFM + c*8);
      v0 = gp[0]; v1 = gp[1];
    }
    u16x8 pk;
    pk[0]=f2b(v0.x); pk[1]=f2b(v0.y); pk[2]=f2b(v0.z); pk[3]=f2b(v0.w);
    pk[4]=f2b(v1.x); pk[5]=f2b(v1.y); pk[6]=f2b(v1.z); pk[7]=f2b(v1.w);
    int byte = row*256 + ((c*16) ^ ((row & 7) << 4));
    *reinterpret_cast<u16x8*>(reinterpret_cast<char*>(lsA) + byte) = pk;
  }
}

// ---- stage 128x128 bf16 weight tile -> swizzled LDS (512 threads) ----
__device__ __forceinline__ void stage_w(u16* lsW, const u16* __restrict__ wt, int t){
  #pragma unroll
  for (int pp = 0; pp < 4; ++pp){
    int id = pp*512 + t;
    int n = id >> 4, c = id & 15;
    u16x8 v = *reinterpret_cast<const u16x8*>(wt + n*NFM + c*8);
    int byte = n*256 + ((c*16) ^ ((n & 7) << 4));
    *reinterpret_cast<u16x8*>(reinterpret_cast<char*>(lsW) + byte) = v;
  }
}

// ---- per-wave 32x128 GEMM, A from swizzled LDS, B from LDS ----
__device__ __forceinline__ void gemm_tile(const u16* lsA, const u16* lsW,
                                          int wrow, int l15, int lk, f32x4 acc[2][8]){
  #pragma unroll
  for (int ks = 0; ks < 4; ++ks){
    int kb2 = (ks*32 + lk*8) * 2;
    int r0 = wrow + l15, r1 = wrow + 16 + l15;
    bf16x8 a0 = *reinterpret_cast<const bf16x8*>(reinterpret_cast<const char*>(lsA) + r0*256 + (kb2 ^ ((r0 & 7) << 4)));
    bf16x8 a1 = *reinterpret_cast<const bf16x8*>(reinterpret_cast<const char*>(lsA) + r1*256 + (kb2 ^ ((r1 & 7) << 4)));
    #pragma unroll
    for (int ni = 0; ni < 8; ++ni){
      int n = ni*16 + l15;
      bf16x8 b = *reinterpret_cast<const bf16x8*>(reinterpret_cast<const char*>(lsW) + n*256 + (kb2 ^ ((n & 7) << 4)));
      acc[0][ni] = __builtin_amdgcn_mfma_f32_16x16x32_bf16(a0, b, acc[0][ni], 0, 0, 0);
      acc[1][ni] = __builtin_amdgcn_mfma_f32_16x16x32_bf16(a1, b, acc[1][ni], 0, 0, 0);
    }
  }
}

// ---- f = x @ W_in2fac, output bf16 ----
__global__ __launch_bounds__(512, 2) void in2fac_k(const float* __restrict__ x,
                                                   const u16* __restrict__ wt,
                                                   u16* __restrict__ f_g){
  __shared__ u16 lsA[256*128];
  __shared__ u16 lsW[128*128];
  int t = threadIdx.x;
  int B0 = blockIdx.x * 256;
  stage_inp(lsA, x, B0, NATOMS, t);
  stage_w(lsW, wt, t);
  __syncthreads();
  int wid = t >> 6, lane = t & 63, l15 = lane & 15, lk = lane >> 4;
  int wrow = wid * 32;
  f32x4 acc[2][8] = {};
  gemm_tile(lsA, lsW, wrow, l15, lk, acc);
  #pragma unroll
  for (int mi = 0; mi < 2; ++mi)
    #pragma unroll
    for (int ni = 0; ni < 8; ++ni)
      #pragma unroll
      for (int j = 0; j < 4; ++j){
        int grow = B0 + wrow + mi*16 + lk*4 + j;
        if (grow < NATOMS) f_g[(size_t)grow*NFM + ni*16 + l15] = f2b(acc[mi][ni][j]);
      }
}

// ---- filter kernel: all 16 A-loads hoisted (nontemporal), 1 barrier ----
__global__ __launch_bounds__(512) __attribute__((amdgpu_waves_per_eu(4, 4)))
void filter_k(const float* __restrict__ dijk,
              const float* __restrict__ b_f1, const float* __restrict__ b_f2,
              const u16* __restrict__ wt1, const u16* __restrict__ wt2,
              u16* __restrict__ w_g){
  __shared__ u16 lsW[2*128*128];   // 64 KB: W1 | W2
  __shared__ u16 lsS[8192];        // 16 KB: 2 KB per-wave scratch
  int t = threadIdx.x;
  int B0 = blockIdx.x * 256;
  int wid = t >> 6, lane = t & 63, l15 = lane & 15, lk = lane >> 4;

  // issue ALL A loads first (16 f32x4/lane, nontemporal) -> overlap W staging
  f32x4 araw[16];
  {
    const float* abase = dijk + (size_t)(B0 + wid*32 + l15) * NFM;
    #pragma unroll
    for (int mi = 0; mi < 2; ++mi)
      #pragma unroll
      for (int ks = 0; ks < 4; ++ks){
        const f32x4* gp = reinterpret_cast<const f32x4*>(abase + mi*16*NFM + ks*32 + lk*8);
        araw[(mi*4+ks)*2+0] = __builtin_nontemporal_load(gp);
        araw[(mi*4+ks)*2+1] = __builtin_nontemporal_load(gp+1);
      }
  }

  stage_w(lsW, wt1, t);
  stage_w(lsW + 16384, wt2, t);

  float bias1[8], bias2[8];
  #pragma unroll
  for (int ni = 0; ni < 8; ++ni){ bias1[ni] = b_f1[ni*16 + l15]; bias2[ni] = b_f2[ni*16 + l15]; }

  // pack to bf16 fragments (araw dies here)
  bf16x8 aa[2][4];
  #pragma unroll
  for (int mi = 0; mi < 2; ++mi)
    #pragma unroll
    for (int ks = 0; ks < 4; ++ks){
      f32x4 v0 = araw[(mi*4+ks)*2], v1 = araw[(mi*4+ks)*2+1];
      u16x8 pk;
      pk[0]=f2b(v0[0]); pk[1]=f2b(v0[1]); pk[2]=f2b(v0[2]); pk[3]=f2b(v0[3]);
      pk[4]=f2b(v1[0]); pk[5]=f2b(v1[1]); pk[6]=f2b(v1[2]); pk[7]=f2b(v1[3]);
      aa[mi][ks] = __builtin_bit_cast(bf16x8, pk);
    }

  __syncthreads();   // W1+W2 ready; everything below is wave-private

  char* wbase = reinterpret_cast<char*>(lsS) + wid*2048;  // [16r][64c] bf16 swizzled
  const char* lsW1b = reinterpret_cast<const char*>(lsW);
  const char* lsW2b = reinterpret_cast<const char*>(lsW + 16384);

  #pragma unroll
  for (int mi = 0; mi < 2; ++mi){
    // GEMM1 full width
    f32x4 acc[8] = {};
    #pragma unroll
    for (int ks = 0; ks < 4; ++ks){
      int kb2 = (ks*32 + lk*8) * 2;
      #pragma unroll
      for (int ni = 0; ni < 8; ++ni){
        int n = ni*16 + l15;
        bf16x8 b = *reinterpret_cast<const bf16x8*>(lsW1b + n*256 + (kb2 ^ ((n & 7) << 4)));
        acc[ni] = __builtin_amdgcn_mfma_f32_16x16x32_bf16(aa[mi][ks], b, acc[ni], 0, 0, 0);
      }
    }
    // h = ssp(acc+b1) via scratch (2 col-halves), reload as k-fragments
    bf16x8 h[4];
    #pragma unroll
    for (int p = 0; p < 2; ++p){
      #pragma unroll
      for (int nn = 0; nn < 4; ++nn){
        int col = nn*16 + l15;
        #pragma unroll
        for (int j = 0; j < 4; ++j){
          int r = lk*4 + j;
          *reinterpret_cast<u16*>(wbase + r*128 + ((col*2) ^ ((r & 7) << 4))) = f2b(sspf(acc[p*4+nn][j] + bias1[p*4+nn]));
        }
      }
      #pragma unroll
      for (int ksl = 0; ksl < 2; ++ksl)
        h[p*2+ksl] = *reinterpret_cast<const bf16x8*>(wbase + l15*128 + ((ksl*64 + lk*16) ^ ((l15 & 7) << 4)));
    }
    // GEMM2 per 64-col half; ssp -> scratch -> coalesced 32B/lane global writes
    #pragma unroll
    for (int p = 0; p < 2; ++p){
      f32x4 acc2[4] = {};
      #pragma unroll
      for (int ks = 0; ks < 4; ++ks){
        int kb2 = (ks*32 + lk*8) * 2;
        #pragma unroll
        for (int nn = 0; nn < 4; ++nn){
          int n = (p*4 + nn)*16 + l15;
          bf16x8 b = *reinterpret_cast<const bf16x8*>(lsW2b + n*256 + (kb2 ^ ((n & 7) << 4)));
          acc2[nn] = __builtin_amdgcn_mfma_f32_16x16x32_bf16(h[ks], b, acc2[nn], 0, 0, 0);
        }
      }
      #pragma unroll
      for (int nn = 0; nn < 4; ++nn){
        int col = nn*16 + l15;
        #pragma unroll
        for (int j = 0; j < 4; ++j){
          int r = lk*4 + j;
          *reinterpret_cast<u16*>(wbase + r*128 + ((col*2) ^ ((r & 7) << 4))) = f2b(sspf(acc2[nn][j] + bias2[p*4+nn]));
        }
      }
      // full 64-col coverage — each lane writes 32 B (2 x u16x8)
      int row16 = lane & 15, chunk = lane >> 4;   // chunk 0..3 -> col base chunk*16
      u16x8 v0 = *reinterpret_cast<const u16x8*>(wbase + row16*128 + ((chunk*32) ^ ((row16 & 7) << 4)));
      u16x8 v1 = *reinterpret_cast<const u16x8*>(wbase + row16*128 + ((chunk*32 + 16) ^ ((row16 & 7) << 4)));
      u16* gdst = w_g + (size_t)(B0 + wid*32 + mi*16 + row16)*NFM + p*64 + chunk*16;
      *reinterpret_cast<u16x8*>(gdst)     = v0;
      *reinterpret_cast<u16x8*>(gdst + 8) = v1;
    }
  }
}

// ---- conv kernel v4: 512-row blocks, 1 col/thread, 128-row chains ->
//      ~1.6M scalar atomics total (16x fewer than v3) ----
__global__ __launch_bounds__(512) void conv_k(const int* __restrict__ idx_j,
    const int* __restrict__ seg_i, const u16* __restrict__ f_g,
    const u16* __restrict__ w_g, float* __restrict__ conv){
  __shared__ int lsSeg[CVROWS];
  __shared__ int lsIdx[CVROWS];
  int t = threadIdx.x;
  int B0 = blockIdx.x * CVROWS;
  int navail = NINT - B0; if (navail > CVROWS) navail = CVROWS;
  if (t < navail){ lsSeg[t] = seg_i[B0 + t]; lsIdx[t] = idx_j[B0 + t]; }
  __syncthreads();
  int col = t & 127, q = t >> 7;       // 4 chunks x 128-row chains, 1 col each
  int qs = q*128;
  if (qs >= navail) return;
  int qe = qs + 128; if (qe > navail) qe = navail;
  int prevseg = (qs > 0) ? lsSeg[qs-1] : (B0 > 0 ? seg_i[B0-1] : -1);
  int nextseg = (qe < navail) ? lsSeg[qe] : (B0 + qe < NINT ? seg_i[B0+qe] : -1);
  const u16* wtile = w_g + (size_t)B0*NFM;
  float s = 0.f;
  int cur = lsSeg[qs], rs = qs;
  #pragma unroll 8
  for (int r = qs; r < qe; ++r){
    int sg = lsSeg[r];
    float wv = b2f(wtile[(size_t)r*NFM + col]);
    float fv = b2f(f_g[(size_t)lsIdx[r]*NFM + col]);
    if (sg != cur){
      float* dp = conv + (size_t)cur*NFM + col;
      if (rs == qs && prevseg == cur) atomicAdd(dp, s); else *dp = s;
      cur = sg; rs = r; s = 0.f;
    }
    s = fmaf(wv, fv, s);
  }
  float* dp = conv + (size_t)cur*NFM + col;
  if ((rs == qs && prevseg == cur) || nextseg == cur) atomicAdd(dp, s); else *dp = s;
}

// ---- c = ssp(conv@W3+b3); v = c@W4+b4; y = x+v; out = [y ; v] ----
__global__ __launch_bounds__(512, 2) void out_k(const float* __restrict__ conv,
    const float* __restrict__ x, const u16* __restrict__ wt3, const u16* __restrict__ wt4,
    const float* __restrict__ b3, const float* __restrict__ b4, float* __restrict__ out){
  __shared__ u16 lsA[256*128];
  __shared__ u16 lsW1[128*128];
  __shared__ u16 lsW2[128*128];
  int t = threadIdx.x;
  int B0 = blockIdx.x * 256;
  stage_inp(lsA, conv, B0, NATOMS, t);
  stage_w(lsW1, wt3, t);
  stage_w(lsW2, wt4, t);
  __syncthreads();
  int wid = t >> 6, lane = t & 63, l15 = lane & 15, lk = lane >> 4;
  int wrow = wid * 32;
  float bias3[8], bias4[8];
  #pragma unroll
  for (int ni = 0; ni < 8; ++ni){ bias3[ni] = b3[ni*16 + l15]; bias4[ni] = b4[ni*16 + l15]; }

  f32x4 acc1[2][8] = {};
  gemm_tile(lsA, lsW1, wrow, l15, lk, acc1);
  #pragma unroll
  for (int mi = 0; mi < 2; ++mi)
    #pragma unroll
    for (int ni = 0; ni < 8; ++ni)
      #pragma unroll
      for (int j = 0; j < 4; ++j){
        int row = wrow + mi*16 + lk*4 + j;
        int col = ni*16 + l15;
        u16 hb = f2b(sspf(acc1[mi][ni][j] + bias3[ni]));
        int byte = row*256 + ((col*2) ^ ((row & 7) << 4));
        *reinterpret_cast<u16*>(reinterpret_cast<char*>(lsA) + byte) = hb;
      }

  f32x4 acc2[2][8] = {};
  gemm_tile(lsA, lsW2, wrow, l15, lk, acc2);
  #pragma unroll
  for (int mi = 0; mi < 2; ++mi)
    #pragma unroll
    for (int ni = 0; ni < 8; ++ni)
      #pragma unroll
      for (int j = 0; j < 4; ++j){
        int grow = B0 + wrow + mi*16 + lk*4 + j;
        if (grow < NATOMS){
          int col = ni*16 + l15;
          float v = acc2[mi][ni][j] + bias4[ni];
          float yv = x[(size_t)grow*NFM + col] + v;
          out[(size_t)grow*NFM + col] = yv;
          out[(size_t)VOFF + (size_t)grow*NFM + col] = v;
        }
      }
}

extern "C" void kernel_launch(void* const* d_in, const int* in_sizes, int n_in,
                              void* d_out, int out_size, void* d_ws, size_t ws_size,
                              hipStream_t stream){
  const float* x        = (const float*)d_in[0];
  const float* dijk     = (const float*)d_in[1];
  const int*   idx_j    = (const int*)d_in[2];
  const int*   seg_i    = (const int*)d_in[3];
  // d_in[4] = seg_j (identity, unused), d_in[5] = seg_i_sum (unused)
  const float* W_f1     = (const float*)d_in[6];
  const float* b_f1     = (const float*)d_in[7];
  const float* W_f2     = (const float*)d_in[8];
  const float* b_f2     = (const float*)d_in[9];
  const float* W_in2fac = (const float*)d_in[10];
  const float* W_fac2o  = (const float*)d_in[11];
  const float* b_fac2o  = (const float*)d_in[12];
  const float* W_dense  = (const float*)d_in[13];
  const float* b_dense  = (const float*)d_in[14];
  float* out = (float*)d_out;

  char* ws = (char*)d_ws;
  u16*   f_g  = (u16*)ws;                         // 12.8 MB (bf16)
  float* conv = (float*)(ws + 12800000);          // 25.6 MB
  u16*   wt   = (u16*)(ws + 38400000);            // 5 x 32 KB
  u16*   w_g  = (u16*)(ws + 38600000);            // 204.8 MB (bf16, ~L3-resident)
  u16* wt1 = wt;             // W_f1^T
  u16* wt2 = wt + 16384;     // W_f2^T
  u16* wt5 = wt + 2*16384;   // W_in2fac^T
  u16* wt3 = wt + 3*16384;   // W_fac2out^T
  u16* wt4 = wt + 4*16384;   // W_dense^T

  prep_weights_k<<<5, 256, 0, stream>>>(W_f1, W_f2, W_in2fac, W_fac2o, W_dense, wt);
  zero_k<<<2048, 256, 0, stream>>>(reinterpret_cast<float4*>(conv), NATOMS*NFM/4);
  in2fac_k<<<(NATOMS + 255)/256, 512, 0, stream>>>(x, wt5, f_g);
  filter_k<<<NBLK, 512, 0, stream>>>(dijk, b_f1, b_f2, wt1, wt2, w_g);
  conv_k<<<CVBLK, 512, 0, stream>>>(idx_j, seg_i, f_g, w_g, conv);
  out_k<<<(NATOMS + 255)/256, 512, 0, stream>>>(conv, x, wt3, wt4, b_fac2o, b_dense, out);
}

// Round 21
// 302.104 us; speedup vs baseline: 1.7581x; 1.0807x over previous
//
#include <hip/hip_runtime.h>
#include <hip/hip_bf16.h>
#include <stdint.h>

#define NATOMS 50000
#define NINT   800000
#define NFM    128
#define VOFF   (NATOMS*NFM)
#define NBLK   (NINT/256)          // 3125 (filter)
#define CVROWS 512
#define CVBLK  ((NINT + CVROWS - 1)/CVROWS)   // 1563 (conv)

typedef __bf16 bf16x8 __attribute__((ext_vector_type(8)));
typedef float  f32x4  __attribute__((ext_vector_type(4)));
typedef unsigned short u16;
typedef u16 u16x8 __attribute__((ext_vector_type(8)));
typedef u16 u16x4 __attribute__((ext_vector_type(4)));

__device__ __forceinline__ u16 f2b(float f){
  __bf16 h = (__bf16)f;
  return __builtin_bit_cast(u16, h);
}
__device__ __forceinline__ float b2f(u16 v){
  return (float)__builtin_bit_cast(__bf16, v);
}

__device__ __forceinline__ float sspf(float x){
  // ssp(x) = ln((1+e^x)/2) = ln2*(log2(1+2^(x*log2e)) - 1); safe for |x|<88
  float t = exp2f(x * 1.44269504088896f);
  return 0.69314718055995f * (log2f(1.0f + t) - 1.0f);
}

// ---- fast zero for conv ----
__global__ void zero_k(float4* __restrict__ p, int n4){
  int i = blockIdx.x * blockDim.x + threadIdx.x;
  int stride = gridDim.x * blockDim.x;
  float4 z = make_float4(0.f, 0.f, 0.f, 0.f);
  for (; i < n4; i += stride) p[i] = z;
}

// ---- weight prep: transpose 128x128 f32 -> bf16 Wt[n][k] = W[k][n] ----
__global__ void prep_weights_k(const float* __restrict__ w0, const float* __restrict__ w1,
                               const float* __restrict__ w2, const float* __restrict__ w3,
                               const float* __restrict__ w4, u16* __restrict__ wt){
  const float* srcs[5] = {w0, w1, w2, w3, w4};
  const float* src = srcs[blockIdx.x];
  u16* dst = wt + (size_t)blockIdx.x * NFM * NFM;
  for (int i = threadIdx.x; i < NFM*NFM; i += blockDim.x){
    int n = i >> 7, k = i & 127;
    dst[i] = f2b(src[k*NFM + n]);
  }
}

// ---- stage 256x128 f32 rows -> swizzled bf16 LDS tile (512 threads) ----
__device__ __forceinline__ void stage_inp(u16* lsA, const float* __restrict__ src,
                                          int base_row, int n_total, int t){
  #pragma unroll
  for (int pp = 0; pp < 8; ++pp){
    int id  = pp*512 + t;
    int row = id >> 4, c = id & 15;
    int grow = base_row + row;
    float4 v0 = make_float4(0.f,0.f,0.f,0.f), v1 = v0;
    if (grow < n_total){
      const float4* gp = reinterpret_cast<const float4*>(src + (size_t)grow*NFM + c*8);
      v0 = gp[0]; v1 = gp[1];
    }
    u16x8 pk;
    pk[0]=f2b(v0.x); pk[1]=f2b(v0.y); pk[2]=f2b(v0.z); pk[3]=f2b(v0.w);
    pk[4]=f2b(v1.x); pk[5]=f2b(v1.y); pk[6]=f2b(v1.z); pk[7]=f2b(v1.w);
    int byte = row*256 + ((c*16) ^ ((row & 7) << 4));
    *reinterpret_cast<u16x8*>(reinterpret_cast<char*>(lsA) + byte) = pk;
  }
}

// ---- stage 128x128 bf16 weight tile -> swizzled LDS (512 threads) ----
__device__ __forceinline__ void stage_w(u16* lsW, const u16* __restrict__ wt, int t){
  #pragma unroll
  for (int pp = 0; pp < 4; ++pp){
    int id = pp*512 + t;
    int n = id >> 4, c = id & 15;
    u16x8 v = *reinterpret_cast<const u16x8*>(wt + n*NFM + c*8);
    int byte = n*256 + ((c*16) ^ ((n & 7) << 4));
    *reinterpret_cast<u16x8*>(reinterpret_cast<char*>(lsW) + byte) = v;
  }
}

// ---- per-wave 32x128 GEMM, A from swizzled LDS, B from LDS ----
__device__ __forceinline__ void gemm_tile(const u16* lsA, const u16* lsW,
                                          int wrow, int l15, int lk, f32x4 acc[2][8]){
  #pragma unroll
  for (int ks = 0; ks < 4; ++ks){
    int kb2 = (ks*32 + lk*8) * 2;
    int r0 = wrow + l15, r1 = wrow + 16 + l15;
    bf16x8 a0 = *reinterpret_cast<const bf16x8*>(reinterpret_cast<const char*>(lsA) + r0*256 + (kb2 ^ ((r0 & 7) << 4)));
    bf16x8 a1 = *reinterpret_cast<const bf16x8*>(reinterpret_cast<const char*>(lsA) + r1*256 + (kb2 ^ ((r1 & 7) << 4)));
    #pragma unroll
    for (int ni = 0; ni < 8; ++ni){
      int n = ni*16 + l15;
      bf16x8 b = *reinterpret_cast<const bf16x8*>(reinterpret_cast<const char*>(lsW) + n*256 + (kb2 ^ ((n & 7) << 4)));
      acc[0][ni] = __builtin_amdgcn_mfma_f32_16x16x32_bf16(a0, b, acc[0][ni], 0, 0, 0);
      acc[1][ni] = __builtin_amdgcn_mfma_f32_16x16x32_bf16(a1, b, acc[1][ni], 0, 0, 0);
    }
  }
}

// ---- f = x @ W_in2fac, output bf16 ----
__global__ __launch_bounds__(512, 2) void in2fac_k(const float* __restrict__ x,
                                                   const u16* __restrict__ wt,
                                                   u16* __restrict__ f_g){
  __shared__ u16 lsA[256*128];
  __shared__ u16 lsW[128*128];
  int t = threadIdx.x;
  int B0 = blockIdx.x * 256;
  stage_inp(lsA, x, B0, NATOMS, t);
  stage_w(lsW, wt, t);
  __syncthreads();
  int wid = t >> 6, lane = t & 63, l15 = lane & 15, lk = lane >> 4;
  int wrow = wid * 32;
  f32x4 acc[2][8] = {};
  gemm_tile(lsA, lsW, wrow, l15, lk, acc);
  #pragma unroll
  for (int mi = 0; mi < 2; ++mi)
    #pragma unroll
    for (int ni = 0; ni < 8; ++ni)
      #pragma unroll
      for (int j = 0; j < 4; ++j){
        int grow = B0 + wrow + mi*16 + lk*4 + j;
        if (grow < NATOMS) f_g[(size_t)grow*NFM + ni*16 + l15] = f2b(acc[mi][ni][j]);
      }
}

// ---- filter kernel: all 16 A-loads hoisted (nontemporal), 1 barrier ----
__global__ __launch_bounds__(512) __attribute__((amdgpu_waves_per_eu(4, 4)))
void filter_k(const float* __restrict__ dijk,
              const float* __restrict__ b_f1, const float* __restrict__ b_f2,
              const u16* __restrict__ wt1, const u16* __restrict__ wt2,
              u16* __restrict__ w_g){
  __shared__ u16 lsW[2*128*128];   // 64 KB: W1 | W2
  __shared__ u16 lsS[8192];        // 16 KB: 2 KB per-wave scratch
  int t = threadIdx.x;
  int B0 = blockIdx.x * 256;
  int wid = t >> 6, lane = t & 63, l15 = lane & 15, lk = lane >> 4;

  // issue ALL A loads first (16 f32x4/lane, nontemporal) -> overlap W staging
  f32x4 araw[16];
  {
    const float* abase = dijk + (size_t)(B0 + wid*32 + l15) * NFM;
    #pragma unroll
    for (int mi = 0; mi < 2; ++mi)
      #pragma unroll
      for (int ks = 0; ks < 4; ++ks){
        const f32x4* gp = reinterpret_cast<const f32x4*>(abase + mi*16*NFM + ks*32 + lk*8);
        araw[(mi*4+ks)*2+0] = __builtin_nontemporal_load(gp);
        araw[(mi*4+ks)*2+1] = __builtin_nontemporal_load(gp+1);
      }
  }

  stage_w(lsW, wt1, t);
  stage_w(lsW + 16384, wt2, t);

  float bias1[8], bias2[8];
  #pragma unroll
  for (int ni = 0; ni < 8; ++ni){ bias1[ni] = b_f1[ni*16 + l15]; bias2[ni] = b_f2[ni*16 + l15]; }

  // pack to bf16 fragments (araw dies here)
  bf16x8 aa[2][4];
  #pragma unroll
  for (int mi = 0; mi < 2; ++mi)
    #pragma unroll
    for (int ks = 0; ks < 4; ++ks){
      f32x4 v0 = araw[(mi*4+ks)*2], v1 = araw[(mi*4+ks)*2+1];
      u16x8 pk;
      pk[0]=f2b(v0[0]); pk[1]=f2b(v0[1]); pk[2]=f2b(v0[2]); pk[3]=f2b(v0[3]);
      pk[4]=f2b(v1[0]); pk[5]=f2b(v1[1]); pk[6]=f2b(v1[2]); pk[7]=f2b(v1[3]);
      aa[mi][ks] = __builtin_bit_cast(bf16x8, pk);
    }

  __syncthreads();   // W1+W2 ready; everything below is wave-private

  char* wbase = reinterpret_cast<char*>(lsS) + wid*2048;  // [16r][64c] bf16 swizzled
  const char* lsW1b = reinterpret_cast<const char*>(lsW);
  const char* lsW2b = reinterpret_cast<const char*>(lsW + 16384);

  #pragma unroll
  for (int mi = 0; mi < 2; ++mi){
    // GEMM1 full width
    f32x4 acc[8] = {};
    #pragma unroll
    for (int ks = 0; ks < 4; ++ks){
      int kb2 = (ks*32 + lk*8) * 2;
      #pragma unroll
      for (int ni = 0; ni < 8; ++ni){
        int n = ni*16 + l15;
        bf16x8 b = *reinterpret_cast<const bf16x8*>(lsW1b + n*256 + (kb2 ^ ((n & 7) << 4)));
        acc[ni] = __builtin_amdgcn_mfma_f32_16x16x32_bf16(aa[mi][ks], b, acc[ni], 0, 0, 0);
      }
    }
    // h = ssp(acc+b1) via scratch (2 col-halves), reload as k-fragments
    bf16x8 h[4];
    #pragma unroll
    for (int p = 0; p < 2; ++p){
      #pragma unroll
      for (int nn = 0; nn < 4; ++nn){
        int col = nn*16 + l15;
        #pragma unroll
        for (int j = 0; j < 4; ++j){
          int r = lk*4 + j;
          *reinterpret_cast<u16*>(wbase + r*128 + ((col*2) ^ ((r & 7) << 4))) = f2b(sspf(acc[p*4+nn][j] + bias1[p*4+nn]));
        }
      }
      #pragma unroll
      for (int ksl = 0; ksl < 2; ++ksl)
        h[p*2+ksl] = *reinterpret_cast<const bf16x8*>(wbase + l15*128 + ((ksl*64 + lk*16) ^ ((l15 & 7) << 4)));
    }
    // GEMM2 per 64-col half; ssp -> scratch -> coalesced 32B/lane global writes
    #pragma unroll
    for (int p = 0; p < 2; ++p){
      f32x4 acc2[4] = {};
      #pragma unroll
      for (int ks = 0; ks < 4; ++ks){
        int kb2 = (ks*32 + lk*8) * 2;
        #pragma unroll
        for (int nn = 0; nn < 4; ++nn){
          int n = (p*4 + nn)*16 + l15;
          bf16x8 b = *reinterpret_cast<const bf16x8*>(lsW2b + n*256 + (kb2 ^ ((n & 7) << 4)));
          acc2[nn] = __builtin_amdgcn_mfma_f32_16x16x32_bf16(h[ks], b, acc2[nn], 0, 0, 0);
        }
      }
      #pragma unroll
      for (int nn = 0; nn < 4; ++nn){
        int col = nn*16 + l15;
        #pragma unroll
        for (int j = 0; j < 4; ++j){
          int r = lk*4 + j;
          *reinterpret_cast<u16*>(wbase + r*128 + ((col*2) ^ ((r & 7) << 4))) = f2b(sspf(acc2[nn][j] + bias2[p*4+nn]));
        }
      }
      // full 64-col coverage — each lane writes 32 B (2 x u16x8)
      int row16 = lane & 15, chunk = lane >> 4;   // chunk 0..3 -> col base chunk*16
      u16x8 v0 = *reinterpret_cast<const u16x8*>(wbase + row16*128 + ((chunk*32) ^ ((row16 & 7) << 4)));
      u16x8 v1 = *reinterpret_cast<const u16x8*>(wbase + row16*128 + ((chunk*32 + 16) ^ ((row16 & 7) << 4)));
      u16* gdst = w_g + (size_t)(B0 + wid*32 + mi*16 + row16)*NFM + p*64 + chunk*16;
      *reinterpret_cast<u16x8*>(gdst)     = v0;
      *reinterpret_cast<u16x8*>(gdst + 8) = v1;
    }
  }
}

// ---- conv kernel v5: 512-row blocks, 1 col/thread, 128-row chains,
//      explicit 16-row load batches (32 loads in flight) to break
//      the VGPR-starved load serialization seen in v4 (VGPR=20) ----
__global__ __launch_bounds__(512) void conv_k(const int* __restrict__ idx_j,
    const int* __restrict__ seg_i, const u16* __restrict__ f_g,
    const u16* __restrict__ w_g, float* __restrict__ conv){
  __shared__ int lsSeg[CVROWS];
  __shared__ int lsIdx[CVROWS];
  int t = threadIdx.x;
  int B0 = blockIdx.x * CVROWS;
  int navail = NINT - B0; if (navail > CVROWS) navail = CVROWS;
  if (t < navail){ lsSeg[t] = seg_i[B0 + t]; lsIdx[t] = idx_j[B0 + t]; }
  __syncthreads();
  int col = t & 127, q = t >> 7;       // 4 chains x 128 rows, 1 col each
  int qs = q*128;
  if (qs >= navail) return;            // live chains always have 128 rows (multiples of 16)
  int qe = qs + 128; if (qe > navail) qe = navail;
  int prevseg = (qs > 0) ? lsSeg[qs-1] : (B0 > 0 ? seg_i[B0-1] : -1);
  int nextseg = (qe < navail) ? lsSeg[qe] : (B0 + qe < NINT ? seg_i[B0+qe] : -1);
  const u16* wtile = w_g + (size_t)B0*NFM;
  float s = 0.f;
  int cur = lsSeg[qs], rs = qs;
  for (int base = qs; base < qe; base += 16){
    // batch-load 16 w + 16 f values (all indices compile-time -> registers)
    float wbuf[16], fbuf[16];
    #pragma unroll
    for (int k = 0; k < 16; ++k){
      int r = base + k;
      wbuf[k] = b2f(wtile[(size_t)r*NFM + col]);
      fbuf[k] = b2f(f_g[(size_t)lsIdx[r]*NFM + col]);
    }
    #pragma unroll
    for (int k = 0; k < 16; ++k){
      int r = base + k;
      int sg = lsSeg[r];
      if (sg != cur){
        float* dp = conv + (size_t)cur*NFM + col;
        if (rs == qs && prevseg == cur) atomicAdd(dp, s); else *dp = s;
        cur = sg; rs = r; s = 0.f;
      }
      s = fmaf(wbuf[k], fbuf[k], s);
    }
  }
  float* dp = conv + (size_t)cur*NFM + col;
  if ((rs == qs && prevseg == cur) || nextseg == cur) atomicAdd(dp, s); else *dp = s;
}

// ---- c = ssp(conv@W3+b3); v = c@W4+b4; y = x+v; out = [y ; v] ----
__global__ __launch_bounds__(512, 2) void out_k(const float* __restrict__ conv,
    const float* __restrict__ x, const u16* __restrict__ wt3, const u16* __restrict__ wt4,
    const float* __restrict__ b3, const float* __restrict__ b4, float* __restrict__ out){
  __shared__ u16 lsA[256*128];
  __shared__ u16 lsW1[128*128];
  __shared__ u16 lsW2[128*128];
  int t = threadIdx.x;
  int B0 = blockIdx.x * 256;
  stage_inp(lsA, conv, B0, NATOMS, t);
  stage_w(lsW1, wt3, t);
  stage_w(lsW2, wt4, t);
  __syncthreads();
  int wid = t >> 6, lane = t & 63, l15 = lane & 15, lk = lane >> 4;
  int wrow = wid * 32;
  float bias3[8], bias4[8];
  #pragma unroll
  for (int ni = 0; ni < 8; ++ni){ bias3[ni] = b3[ni*16 + l15]; bias4[ni] = b4[ni*16 + l15]; }

  f32x4 acc1[2][8] = {};
  gemm_tile(lsA, lsW1, wrow, l15, lk, acc1);
  #pragma unroll
  for (int mi = 0; mi < 2; ++mi)
    #pragma unroll
    for (int ni = 0; ni < 8; ++ni)
      #pragma unroll
      for (int j = 0; j < 4; ++j){
        int row = wrow + mi*16 + lk*4 + j;
        int col = ni*16 + l15;
        u16 hb = f2b(sspf(acc1[mi][ni][j] + bias3[ni]));
        int byte = row*256 + ((col*2) ^ ((row & 7) << 4));
        *reinterpret_cast<u16*>(reinterpret_cast<char*>(lsA) + byte) = hb;
      }

  f32x4 acc2[2][8] = {};
  gemm_tile(lsA, lsW2, wrow, l15, lk, acc2);
  #pragma unroll
  for (int mi = 0; mi < 2; ++mi)
    #pragma unroll
    for (int ni = 0; ni < 8; ++ni)
      #pragma unroll
      for (int j = 0; j < 4; ++j){
        int grow = B0 + wrow + mi*16 + lk*4 + j;
        if (grow < NATOMS){
          int col = ni*16 + l15;
          float v = acc2[mi][ni][j] + bias4[ni];
          float yv = x[(size_t)grow*NFM + col] + v;
          out[(size_t)grow*NFM + col] = yv;
          out[(size_t)VOFF + (size_t)grow*NFM + col] = v;
        }
      }
}

extern "C" void kernel_launch(void* const* d_in, const int* in_sizes, int n_in,
                              void* d_out, int out_size, void* d_ws, size_t ws_size,
                              hipStream_t stream){
  const float* x        = (const float*)d_in[0];
  const float* dijk     = (const float*)d_in[1];
  const int*   idx_j    = (const int*)d_in[2];
  const int*   seg_i    = (const int*)d_in[3];
  // d_in[4] = seg_j (identity, unused), d_in[5] = seg_i_sum (unused)
  const float* W_f1     = (const float*)d_in[6];
  const float* b_f1     = (const float*)d_in[7];
  const float* W_f2     = (const float*)d_in[8];
  const float* b_f2     = (const float*)d_in[9];
  const float* W_in2fac = (const float*)d_in[10];
  const float* W_fac2o  = (const float*)d_in[11];
  const float* b_fac2o  = (const float*)d_in[12];
  const float* W_dense  = (const float*)d_in[13];
  const float* b_dense  = (const float*)d_in[14];
  float* out = (float*)d_out;

  char* ws = (char*)d_ws;
  u16*   f_g  = (u16*)ws;                         // 12.8 MB (bf16)
  float* conv = (float*)(ws + 12800000);          // 25.6 MB
  u16*   wt   = (u16*)(ws + 38400000);            // 5 x 32 KB
  u16*   w_g  = (u16*)(ws + 38600000);            // 204.8 MB (bf16, ~L3-resident)
  u16* wt1 = wt;             // W_f1^T
  u16* wt2 = wt + 16384;     // W_f2^T
  u16* wt5 = wt + 2*16384;   // W_in2fac^T
  u16* wt3 = wt + 3*16384;   // W_fac2out^T
  u16* wt4 = wt + 4*16384;   // W_dense^T

  prep_weights_k<<<5, 256, 0, stream>>>(W_f1, W_f2, W_in2fac, W_fac2o, W_dense, wt);
  zero_k<<<2048, 256, 0, stream>>>(reinterpret_cast<float4*>(conv), NATOMS*NFM/4);
  in2fac_k<<<(NATOMS + 255)/256, 512, 0, stream>>>(x, wt5, f_g);
  filter_k<<<NBLK, 512, 0, stream>>>(dijk, b_f1, b_f2, wt1, wt2, w_g);
  conv_k<<<CVBLK, 512, 0, stream>>>(idx_j, seg_i, f_g, w_g, conv);
  out_k<<<(NATOMS + 255)/256, 512, 0, stream>>>(conv, x, wt3, wt4, b_fac2o, b_dense, out);
}